// Round 5
// baseline (231.959 us; speedup 1.0000x reference)
//
#include <hip/hip_runtime.h>
#include <hip/hip_bf16.h>

typedef __bf16 bf16;
typedef __attribute__((ext_vector_type(8))) __bf16 bf16x8;
typedef __attribute__((ext_vector_type(4))) __bf16 bf16x4;
typedef __attribute__((ext_vector_type(4))) float f32x4;

#define MFMA16(a, b, c) __builtin_amdgcn_mfma_f32_16x16x32_bf16((a), (b), (c), 0, 0, 0)

constexpr int Bn = 2, Tn = 2048, Cn = 1024, Hn = 16, Dn = 64;
constexpr int Mn = Bn * Tn;
constexpr int WSZ = Cn * Cn;
constexpr int XSZ = Mn * Cn;
constexpr float LOG2E = 1.44269504088896f;

// async global->LDS, 16B/lane: LDS dest = wave-uniform base + lane*16
__device__ __forceinline__ void async_cp16(bf16* lds, const bf16* g) {
  __builtin_amdgcn_global_load_lds(
      (const __attribute__((address_space(1))) unsigned int*)g,
      (__attribute__((address_space(3))) unsigned int*)lds, 16, 0, 0);
}

struct GemmArgs {
  const bf16* A[3];
  const bf16* Bt[3];
  const float* bias[3];
  void* out[3];
  float scale[3];
  int layout[3];   // 0 = fp32 [M,N]; 1 = bf16 [B,H,T,D]; 2 = bf16 [B,H,D,T]
};

struct TransArgs {
  const float* W[4];
  bf16* Wt[4];
};

struct ConvArgs {
  const float* src[3];
};

// ---------------- fp32 -> bf16 bulk convert (query/key/value) ----------------
__global__ __launch_bounds__(256) void convert_bf16(ConvArgs ca, bf16* __restrict__ dst) {
  const int z = blockIdx.y;
  const float* __restrict__ s = ca.src[z];
  size_t idx = ((size_t)blockIdx.x * 256 + threadIdx.x) * 8;
  float4 a = *(const float4*)&s[idx];
  float4 b = *(const float4*)&s[idx + 4];
  bf16x8 o = {(bf16)a.x, (bf16)a.y, (bf16)a.z, (bf16)a.w,
              (bf16)b.x, (bf16)b.y, (bf16)b.z, (bf16)b.w};
  *(bf16x8*)&dst[(size_t)z * XSZ + idx] = o;
}

// ---------------- W[k][n] fp32 -> Wt[n][k] bf16 (4 weights via grid.z) ----------------
__global__ __launch_bounds__(256) void transpose_convert(TransArgs ta) {
  const float* __restrict__ W = ta.W[blockIdx.z];
  bf16* __restrict__ Wt = ta.Wt[blockIdx.z];
  __shared__ float tile[32][33];
  const int tx = threadIdx.x, ty = threadIdx.y;  // (32,8)
  const int x = blockIdx.x * 32 + tx;
  const int y0 = blockIdx.y * 32;
  for (int j = 0; j < 32; j += 8) tile[ty + j][tx] = W[(y0 + ty + j) * Cn + x];
  __syncthreads();
  const int n0 = blockIdx.x * 32;
  const int k = blockIdx.y * 32 + tx;
  for (int j = 0; j < 32; j += 8)
    Wt[(n0 + ty + j) * Cn + k] = (bf16)tile[tx][ty + j];
}

// ---------------- GEMM: C[M,N] = A[M,K] @ Wt[N,K]^T + bias ----------------
// BM x 128 tile, BK=64, async 16B staging, XOR chunk swizzle -> conflict-free b128 reads.
template <int BM>
__global__ __launch_bounds__(256) void gemm_kernel(GemmArgs args, int K) {
  constexpr int MT = BM / 32;          // m-tiles per wave
  const int z = blockIdx.z;
  const bf16* __restrict__ A = args.A[z];
  const bf16* __restrict__ Bt = args.Bt[z];
  const float* __restrict__ bias = args.bias[z];
  const float scale = args.scale[z];
  const int layout = args.layout[z];

  __shared__ bf16 As[BM * 64];
  __shared__ bf16 Bs[128 * 64];

  const int tid = threadIdx.x;
  const int w = tid >> 6, lane = tid & 63;
  const int wm = w >> 1, wn = w & 1;
  const int g = lane >> 4, l15 = lane & 15;
  const int r8 = lane >> 3, c8 = lane & 7;
  const int soff = (c8 ^ r8) << 3;
  const int kk = l15 & 7;
  const int off0 = (g ^ kk) << 3;
  const int off1 = ((4 + g) ^ kk) << 3;
  const int m0 = blockIdx.y * BM, n0 = blockIdx.x * 128;

  f32x4 acc[MT][4] = {};

  for (int k0 = 0; k0 < K; k0 += 64) {
    __syncthreads();
    for (int i = 0; i < BM / 32; i++) {
      int p = w * (BM / 32) + i;
      async_cp16(&As[p * 512], &A[(size_t)(m0 + p * 8 + r8) * K + k0 + soff]);
    }
    for (int i = 0; i < 4; i++) {
      int p = w * 4 + i;
      async_cp16(&Bs[p * 512], &Bt[(size_t)(n0 + p * 8 + r8) * K + k0 + soff]);
    }
    __syncthreads();

    for (int ks = 0; ks < 2; ks++) {
      const int off = ks ? off1 : off0;
      bf16x8 af[MT], bfr[4];
      for (int mt = 0; mt < MT; mt++)
        af[mt] = *(const bf16x8*)&As[(wm * (BM / 2) + mt * 16 + l15) * 64 + off];
      for (int nt = 0; nt < 4; nt++)
        bfr[nt] = *(const bf16x8*)&Bs[(wn * 64 + nt * 16 + l15) * 64 + off];
      for (int mt = 0; mt < MT; mt++)
        for (int nt = 0; nt < 4; nt++)
          acc[mt][nt] = MFMA16(af[mt], bfr[nt], acc[mt][nt]);
    }
  }

  // epilogue: C/D layout row=(lane>>4)*4+r, col=lane&15
  for (int mt = 0; mt < MT; mt++) {
    for (int nt = 0; nt < 4; nt++) {
      int gn = n0 + wn * 64 + nt * 16 + l15;
      float bb = bias[gn];
      int gm0 = m0 + wm * (BM / 2) + mt * 16 + g * 4;
      float v[4];
      for (int r = 0; r < 4; r++) v[r] = (acc[mt][nt][r] + bb) * scale;
      if (layout == 2) {
        // V^T: bf16 [B,H,D,T]; r -> consecutive t
        int b = gm0 >> 11, t = gm0 & 2047, h = gn >> 6, d = gn & 63;
        bf16x4 ov = {(bf16)v[0], (bf16)v[1], (bf16)v[2], (bf16)v[3]};
        *(bf16x4*)&((bf16*)args.out[z])[(size_t)((b * Hn + h) * Dn + d) * Tn + t] = ov;
      } else if (layout == 1) {
        int b = gm0 >> 11, t = gm0 & 2047, h = gn >> 6, d = gn & 63;
        bf16* o = (bf16*)args.out[z] + (size_t)((b * Hn + h) * Tn + t) * Dn + d;
        for (int r = 0; r < 4; r++) o[(size_t)r * Dn] = (bf16)v[r];
      } else {
        float* o = (float*)args.out[z] + (size_t)gm0 * Cn + gn;
        for (int r = 0; r < 4; r++) o[(size_t)r * Cn] = v[r];
      }
    }
  }
}

// ---------------- Flash attention v9 ----------------
// v8 (PV deferred one tile; exp(t) interleaved with PV(t-1)) measured 58.6us:
// VALUBusy 46 + MfmaUtil 23.5 = ~70% -> ~30% wait. The wait is the loop's
// __syncthreads(): vmcnt(0) drains the K/V prefetch issued only ONE iteration
// earlier -> every wave eats residual HBM/L2 latency at the barrier.
// v9: DEPTH-2 PREFETCH, triple-buffered K/V, counted-vmcnt barrier (T3/T4).
// Each wave issues exactly 4 global_load_lds per tile, so
//   s_waitcnt vmcnt(4)  ==  "tile t+1 complete; tile t+2 may stay in flight".
// waitcnt+s_barrier fused in ONE asm volatile so no LDS op can be scheduled
// between them. lgkmcnt(0) kept in the fence: my vf/pf ds_reads of buf b must
// retire before other waves' post-barrier prefetch (which targets the same
// buf b, 3-deep rotation) can land. Loads now get ~2 full iterations of slack.
constexpr int LDP = 72;
constexpr int NTt = Tn / 64;   // 32 kv tiles

struct PvOn  { static constexpr bool value = true;  };
struct PvOff { static constexpr bool value = false; };

__global__ __launch_bounds__(256) void attn_kernel(const bf16* __restrict__ Qh,
                                                   const bf16* __restrict__ Kh,
                                                   const bf16* __restrict__ VhT,
                                                   bf16* __restrict__ AO) {
  __shared__ bf16 Ks[3][64 * 64];   // [kv][d], chunk-swizzled, triple-buffered
  __shared__ bf16 Vt[3][64 * 64];   // [d][kv], chunk-swizzled, triple-buffered
  __shared__ bf16 Pt[128 * LDP];    // [q][kv], wave-private rows (no barrier)

  const int tid = threadIdx.x;
  const int w = tid >> 6, lane = tid & 63;
  const int g = lane >> 4, l15 = lane & 15;
  const int id = blockIdx.x;
  const int bh = id & 31;           // low bits -> same-bh blocks share an XCD
  const int q0 = (id >> 5) * 128;
  const size_t hb = (size_t)bh * Tn * Dn;
  const size_t hbT = (size_t)bh * Dn * Tn;
  const int r8 = lane >> 3, c8 = lane & 7;
  const int soff = (c8 ^ r8) << 3;
  const int kk = l15 & 7;
  const int off0 = (g ^ kk) << 3;
  const int off1 = ((4 + g) ^ kk) << 3;

  // Q fragments from global (B-operand of S^T)
  bf16x8 qf[2][2];
  for (int qt = 0; qt < 2; qt++) {
    const bf16* qp = Qh + hb + (size_t)(q0 + w * 32 + qt * 16 + l15) * Dn + g * 8;
    qf[qt][0] = *(const bf16x8*)qp;
    qf[qt][1] = *(const bf16x8*)(qp + 32);
  }

  f32x4 o[2][4] = {};
  float l_run[2] = {0.f, 0.f};
  bf16x8 vf[4][2];   // V^T frags of tile t, consumed by PV in iter t+1
  bf16x8 pf[2][2];   // P  frags [qt][ks] of tile t, consumed in iter t+1
  bf16* prow0 = &Pt[(size_t)(w * 32 + l15) * LDP];
  bf16* prow1 = &Pt[(size_t)(w * 32 + 16 + l15) * LDP];

  // prologue: stage tiles 0 and 1 into bufs 0 and 1 (4 loads/wave per tile)
  for (int t = 0; t < 2; t++) {
    for (int i = 0; i < 2; i++) {
      int p = w * 2 + i;
      async_cp16(&Ks[t][p * 512], &Kh[hb + (size_t)(t * 64 + p * 8 + r8) * Dn + soff]);
      async_cp16(&Vt[t][p * 512], &VhT[hbT + (size_t)(p * 8 + r8) * Tn + t * 64 + soff]);
    }
  }
  // tile 0 ready; tile 1's 4 loads may stay in flight
  asm volatile("s_waitcnt vmcnt(4) lgkmcnt(0)\n\ts_barrier" ::: "memory");

  auto body = [&](int kt, int cur, auto pvtag) {
    constexpr bool PV = decltype(pvtag)::value;
    // prefetch tile kt+2 into buffer (cur+2)%3
    if (kt + 2 < NTt) {
      int bp = cur + 2; if (bp >= 3) bp -= 3;
      const int t2 = (kt + 2) * 64;
      for (int i = 0; i < 2; i++) {
        int p = w * 2 + i;
        async_cp16(&Ks[bp][p * 512], &Kh[hb + (size_t)(t2 + p * 8 + r8) * Dn + soff]);
        async_cp16(&Vt[bp][p * 512], &VhT[hbT + (size_t)(p * 8 + r8) * Tn + t2 + soff]);
      }
    }

    // S^T = K Q^T (K-frags shared across the 2 q-tiles)
    f32x4 s[2][4] = {};
    __builtin_amdgcn_s_setprio(1);
    for (int nt = 0; nt < 4; nt++) {
      const bf16* kp = &Ks[cur][(nt * 16 + l15) * 64];
      bf16x8 kf0 = *(const bf16x8*)(kp + off0);
      bf16x8 kf1 = *(const bf16x8*)(kp + off1);
      s[0][nt] = MFMA16(kf0, qf[0][0], s[0][nt]);
      s[0][nt] = MFMA16(kf1, qf[0][1], s[0][nt]);
      s[1][nt] = MFMA16(kf0, qf[1][0], s[1][nt]);
      s[1][nt] = MFMA16(kf1, qf[1][1], s[1][nt]);
    }
    __builtin_amdgcn_s_setprio(0);

    // qt=0: exp(t) interleaved with PV(t-1) for o[0] (independent streams)
    {
      float rs = 0.f;
      for (int nt = 0; nt < 4; nt++) {
        float pe[4];
        for (int r = 0; r < 4; r++) {
          pe[r] = __builtin_amdgcn_exp2f(s[0][nt][r]);
          rs += pe[r];
        }
        bf16x4 p4 = {(bf16)pe[0], (bf16)pe[1], (bf16)pe[2], (bf16)pe[3]};
        *(bf16x4*)&prow0[nt * 16 + g * 4] = p4;
        if constexpr (PV) {
          o[0][nt] = MFMA16(vf[nt][0], pf[0][0], o[0][nt]);
          o[0][nt] = MFMA16(vf[nt][1], pf[0][1], o[0][nt]);
        }
      }
      l_run[0] += rs;
    }
    // new pf[0] (old one fully consumed above); same-wave LDS is in-order,
    // so these reads see this iter's prow0 writes.
    pf[0][0] = *(const bf16x8*)&prow0[g * 8];
    pf[0][1] = *(const bf16x8*)&prow0[32 + g * 8];

    // qt=1: exp(t) interleaved with PV(t-1) for o[1]
    {
      float rs = 0.f;
      for (int nt = 0; nt < 4; nt++) {
        float pe[4];
        for (int r = 0; r < 4; r++) {
          pe[r] = __builtin_amdgcn_exp2f(s[1][nt][r]);
          rs += pe[r];
        }
        bf16x4 p4 = {(bf16)pe[0], (bf16)pe[1], (bf16)pe[2], (bf16)pe[3]};
        *(bf16x4*)&prow1[nt * 16 + g * 4] = p4;
        if constexpr (PV) {
          o[1][nt] = MFMA16(vf[nt][0], pf[1][0], o[1][nt]);
          o[1][nt] = MFMA16(vf[nt][1], pf[1][1], o[1][nt]);
        }
      }
      l_run[1] += rs;
    }
    pf[1][0] = *(const bf16x8*)&prow1[g * 8];
    pf[1][1] = *(const bf16x8*)&prow1[32 + g * 8];

    // new V^T frags for next iter's PV (old vf fully consumed above).
    // Latency hidden under the barrier + next iter's S phase.
    for (int dt = 0; dt < 4; dt++) {
      const bf16* vp = &Vt[cur][(dt * 16 + l15) * 64];
      vf[dt][0] = *(const bf16x8*)(vp + off0);
      vf[dt][1] = *(const bf16x8*)(vp + off1);
    }

    // counted-vmcnt barrier: tile kt+1 ready (oldest 4 loads retired); the 4
    // newest (tile kt+2) stay in flight across the barrier. lgkmcnt(0) makes
    // the pre-barrier ds_reads retire before any post-barrier overwrite.
    if (kt < NTt - 1) {
      if (kt + 2 < NTt)
        asm volatile("s_waitcnt vmcnt(4) lgkmcnt(0)\n\ts_barrier" ::: "memory");
      else
        asm volatile("s_waitcnt vmcnt(0) lgkmcnt(0)\n\ts_barrier" ::: "memory");
    }
  };

  body(0, 0, PvOff{});
  {
    int cur = 1;
    for (int kt = 1; kt < NTt; kt++) {
      body(kt, cur, PvOn{});
      cur = (cur == 2) ? 0 : cur + 1;
    }
  }

  // epilogue PV for the last tile
  __builtin_amdgcn_s_setprio(1);
  for (int nt = 0; nt < 4; nt++) {
    o[0][nt] = MFMA16(vf[nt][0], pf[0][0], o[0][nt]);
    o[0][nt] = MFMA16(vf[nt][1], pf[0][1], o[0][nt]);
    o[1][nt] = MFMA16(vf[nt][0], pf[1][0], o[1][nt]);
    o[1][nt] = MFMA16(vf[nt][1], pf[1][1], o[1][nt]);
  }
  __builtin_amdgcn_s_setprio(0);

  // reduce l across the 4 g-groups (once), normalize, store
  const int b = bh >> 4, h = bh & 15;
  for (int qt = 0; qt < 2; qt++) {
    float l = l_run[qt];
    l += __shfl_xor(l, 16);
    l += __shfl_xor(l, 32);
    float inv = 1.0f / l;
    int qrow = q0 + w * 32 + qt * 16 + l15;
    bf16* orow = AO + (size_t)(b * Tn + qrow) * Cn + h * Dn;
    for (int dt = 0; dt < 4; dt++) {
      bf16x4 ov = {(bf16)(o[qt][dt][0] * inv), (bf16)(o[qt][dt][1] * inv),
                   (bf16)(o[qt][dt][2] * inv), (bf16)(o[qt][dt][3] * inv)};
      *(bf16x4*)&orow[dt * 16 + g * 4] = ov;
    }
  }
}

extern "C" void kernel_launch(void* const* d_in, const int* in_sizes, int n_in,
                              void* d_out, int out_size, void* d_ws, size_t ws_size,
                              hipStream_t stream) {
  const float* query = (const float*)d_in[0];
  const float* key   = (const float*)d_in[1];
  const float* value = (const float*)d_in[2];
  const float* Wq = (const float*)d_in[3];
  const float* bq = (const float*)d_in[4];
  const float* Wk = (const float*)d_in[5];
  const float* bk = (const float*)d_in[6];
  const float* Wv = (const float*)d_in[7];
  const float* bv = (const float*)d_in[8];
  const float* Wo = (const float*)d_in[9];
  const float* bo = (const float*)d_in[10];

  bf16* p = (bf16*)d_ws;
  bf16* WqT = p; p += WSZ;
  bf16* WkT = p; p += WSZ;
  bf16* WvT = p; p += WSZ;
  bf16* WoT = p; p += WSZ;
  bf16* Xbf = p; p += 3 * XSZ;   // bf16 activations; reused as AO after QKV GEMM
  bf16* Qh = p; p += XSZ;
  bf16* Kh = p; p += XSZ;
  bf16* VhT = p; p += XSZ;
  bf16* AO = Xbf;

  TransArgs ta;
  ta.W[0] = Wq; ta.W[1] = Wk; ta.W[2] = Wv; ta.W[3] = Wo;
  ta.Wt[0] = WqT; ta.Wt[1] = WkT; ta.Wt[2] = WvT; ta.Wt[3] = WoT;
  transpose_convert<<<dim3(32, 32, 4), dim3(32, 8), 0, stream>>>(ta);

  ConvArgs ca;
  ca.src[0] = query; ca.src[1] = key; ca.src[2] = value;
  convert_bf16<<<dim3(XSZ / 2048, 3), 256, 0, stream>>>(ca, Xbf);

  GemmArgs ga;
  ga.A[0] = Xbf; ga.A[1] = Xbf + XSZ; ga.A[2] = Xbf + 2 * XSZ;
  ga.Bt[0] = WqT;  ga.Bt[1] = WkT; ga.Bt[2] = WvT;
  ga.bias[0] = bq; ga.bias[1] = bk; ga.bias[2] = bv;
  ga.out[0] = Qh;  ga.out[1] = Kh;  ga.out[2] = VhT;
  ga.scale[0] = 0.125f * LOG2E; ga.scale[1] = 1.0f; ga.scale[2] = 1.0f;
  ga.layout[0] = 1; ga.layout[1] = 1; ga.layout[2] = 2;
  gemm_kernel<128><<<dim3(Cn / 128, Mn / 128, 3), 256, 0, stream>>>(ga, Cn);

  attn_kernel<<<dim3(512), 256, 0, stream>>>(Qh, Kh, VhT, AO);

  GemmArgs gb;
  gb.A[0] = AO; gb.Bt[0] = WoT; gb.bias[0] = bo; gb.out[0] = d_out; gb.scale[0] = 1.0f;
  gb.layout[0] = 0;
  gb.A[1] = gb.A[2] = nullptr; gb.Bt[1] = gb.Bt[2] = nullptr;
  gb.bias[1] = gb.bias[2] = nullptr; gb.out[1] = gb.out[2] = nullptr;
  gb.scale[1] = gb.scale[2] = 1.0f; gb.layout[1] = gb.layout[2] = 0;
  gemm_kernel<64><<<dim3(Cn / 128, Mn / 64, 1), 256, 0, stream>>>(gb, Cn);
}

// Round 7
// 219.440 us; speedup vs baseline: 1.0571x; 1.0571x over previous
//
#include <hip/hip_runtime.h>
#include <hip/hip_bf16.h>

typedef __bf16 bf16;
typedef __attribute__((ext_vector_type(8))) __bf16 bf16x8;
typedef __attribute__((ext_vector_type(4))) __bf16 bf16x4;
typedef __attribute__((ext_vector_type(4))) float f32x4;
typedef __attribute__((ext_vector_type(16))) float f32x16;
typedef __attribute__((ext_vector_type(4))) unsigned int u32x4;

#define MFMA16(a, b, c) __builtin_amdgcn_mfma_f32_16x16x32_bf16((a), (b), (c), 0, 0, 0)
#define MFMA32(a, b, c) __builtin_amdgcn_mfma_f32_32x32x16_bf16((a), (b), (c), 0, 0, 0)

constexpr int Bn = 2, Tn = 2048, Cn = 1024, Hn = 16, Dn = 64;
constexpr int Mn = Bn * Tn;
constexpr int WSZ = Cn * Cn;
constexpr int XSZ = Mn * Cn;
constexpr float LOG2E = 1.44269504088896f;

// async global->LDS, 16B/lane: LDS dest = wave-uniform base + lane*16
__device__ __forceinline__ void async_cp16(bf16* lds, const bf16* g) {
  __builtin_amdgcn_global_load_lds(
      (const __attribute__((address_space(1))) unsigned int*)g,
      (__attribute__((address_space(3))) unsigned int*)lds, 16, 0, 0);
}

__device__ __forceinline__ unsigned int cvtpk(float lo, float hi) {
  unsigned int r;
  asm("v_cvt_pk_bf16_f32 %0, %1, %2" : "=v"(r) : "v"(lo), "v"(hi));
  return r;
}

struct GemmArgs {
  const bf16* A[3];
  const bf16* Bt[3];
  const float* bias[3];
  void* out[3];
  float scale[3];
  int layout[3];   // 0 = fp32 [M,N]; 1 = bf16 [B,H,T,D]; 2 = bf16 [B,H,D,T]
};

struct TransArgs {
  const float* W[4];
  bf16* Wt[4];
};

struct ConvArgs {
  const float* src[3];
};

// ---------------- fp32 -> bf16 bulk convert (query/key/value) ----------------
__global__ __launch_bounds__(256) void convert_bf16(ConvArgs ca, bf16* __restrict__ dst) {
  const int z = blockIdx.y;
  const float* __restrict__ s = ca.src[z];
  size_t idx = ((size_t)blockIdx.x * 256 + threadIdx.x) * 8;
  float4 a = *(const float4*)&s[idx];
  float4 b = *(const float4*)&s[idx + 4];
  bf16x8 o = {(bf16)a.x, (bf16)a.y, (bf16)a.z, (bf16)a.w,
              (bf16)b.x, (bf16)b.y, (bf16)b.z, (bf16)b.w};
  *(bf16x8*)&dst[(size_t)z * XSZ + idx] = o;
}

// ---------------- W[k][n] fp32 -> Wt[n][k] bf16 (4 weights via grid.z) ----------------
__global__ __launch_bounds__(256) void transpose_convert(TransArgs ta) {
  const float* __restrict__ W = ta.W[blockIdx.z];
  bf16* __restrict__ Wt = ta.Wt[blockIdx.z];
  __shared__ float tile[32][33];
  const int tx = threadIdx.x, ty = threadIdx.y;  // (32,8)
  const int x = blockIdx.x * 32 + tx;
  const int y0 = blockIdx.y * 32;
  for (int j = 0; j < 32; j += 8) tile[ty + j][tx] = W[(y0 + ty + j) * Cn + x];
  __syncthreads();
  const int n0 = blockIdx.x * 32;
  const int k = blockIdx.y * 32 + tx;
  for (int j = 0; j < 32; j += 8)
    Wt[(n0 + ty + j) * Cn + k] = (bf16)tile[tx][ty + j];
}

// ---------------- GEMM: C[M,N] = A[M,K] @ Wt[N,K]^T + bias ----------------
// BM x 128 tile, BK=64, async 16B staging, XOR chunk swizzle -> conflict-free b128 reads.
template <int BM>
__global__ __launch_bounds__(256) void gemm_kernel(GemmArgs args, int K) {
  constexpr int MT = BM / 32;          // m-tiles per wave
  const int z = blockIdx.z;
  const bf16* __restrict__ A = args.A[z];
  const bf16* __restrict__ Bt = args.Bt[z];
  const float* __restrict__ bias = args.bias[z];
  const float scale = args.scale[z];
  const int layout = args.layout[z];

  __shared__ bf16 As[BM * 64];
  __shared__ bf16 Bs[128 * 64];

  const int tid = threadIdx.x;
  const int w = tid >> 6, lane = tid & 63;
  const int wm = w >> 1, wn = w & 1;
  const int g = lane >> 4, l15 = lane & 15;
  const int r8 = lane >> 3, c8 = lane & 7;
  const int soff = (c8 ^ r8) << 3;
  const int kk = l15 & 7;
  const int off0 = (g ^ kk) << 3;
  const int off1 = ((4 + g) ^ kk) << 3;
  const int m0 = blockIdx.y * BM, n0 = blockIdx.x * 128;

  f32x4 acc[MT][4] = {};

  for (int k0 = 0; k0 < K; k0 += 64) {
    __syncthreads();
    for (int i = 0; i < BM / 32; i++) {
      int p = w * (BM / 32) + i;
      async_cp16(&As[p * 512], &A[(size_t)(m0 + p * 8 + r8) * K + k0 + soff]);
    }
    for (int i = 0; i < 4; i++) {
      int p = w * 4 + i;
      async_cp16(&Bs[p * 512], &Bt[(size_t)(n0 + p * 8 + r8) * K + k0 + soff]);
    }
    __syncthreads();

    for (int ks = 0; ks < 2; ks++) {
      const int off = ks ? off1 : off0;
      bf16x8 af[MT], bfr[4];
      for (int mt = 0; mt < MT; mt++)
        af[mt] = *(const bf16x8*)&As[(wm * (BM / 2) + mt * 16 + l15) * 64 + off];
      for (int nt = 0; nt < 4; nt++)
        bfr[nt] = *(const bf16x8*)&Bs[(wn * 64 + nt * 16 + l15) * 64 + off];
      for (int mt = 0; mt < MT; mt++)
        for (int nt = 0; nt < 4; nt++)
          acc[mt][nt] = MFMA16(af[mt], bfr[nt], acc[mt][nt]);
    }
  }

  // epilogue: C/D layout row=(lane>>4)*4+r, col=lane&15
  for (int mt = 0; mt < MT; mt++) {
    for (int nt = 0; nt < 4; nt++) {
      int gn = n0 + wn * 64 + nt * 16 + l15;
      float bb = bias[gn];
      int gm0 = m0 + wm * (BM / 2) + mt * 16 + g * 4;
      float v[4];
      for (int r = 0; r < 4; r++) v[r] = (acc[mt][nt][r] + bb) * scale;
      if (layout == 2) {
        // V^T: bf16 [B,H,D,T]; r -> consecutive t
        int b = gm0 >> 11, t = gm0 & 2047, h = gn >> 6, d = gn & 63;
        bf16x4 ov = {(bf16)v[0], (bf16)v[1], (bf16)v[2], (bf16)v[3]};
        *(bf16x4*)&((bf16*)args.out[z])[(size_t)((b * Hn + h) * Dn + d) * Tn + t] = ov;
      } else if (layout == 1) {
        int b = gm0 >> 11, t = gm0 & 2047, h = gn >> 6, d = gn & 63;
        bf16* o = (bf16*)args.out[z] + (size_t)((b * Hn + h) * Tn + t) * Dn + d;
        for (int r = 0; r < 4; r++) o[(size_t)r * Dn] = (bf16)v[r];
      } else {
        float* o = (float*)args.out[z] + (size_t)gm0 * Cn + gn;
        for (int r = 0; r < 4; r++) o[(size_t)r * Cn] = v[r];
      }
    }
  }
}

// ---------------- Flash attention v10 ----------------
// Post-mortem v9: depth-2 prefetch + counted vmcnt REGRESSED (58.6->61.5us) ->
// the wait is NOT global-load drain. Reverted to v8 sync (double buffer,
// __syncthreads per tile, deferred PV interleaved with exp).
// v10 = T12: 32x32x16 MFMA + fully in-register softmax. Each lane owns ONE
// q-row (C col = lane&31), so P partials are lane-local: pack with
// v_cvt_pk_bf16_f32 pairs + permlane32_swap (16 cvt + 8 swaps per tile pair).
// Pt LDS is GONE: no ds_write/ds_read P round-trip (~120cy chain), no Pt bank
// conflicts, 12 fewer ds-ops/wave-iter, l-reduce is a single shfl_xor(32).
// Fragment maps (verified formulas):
//   A 32x32x16: m=lane&31, k=(lane>>5)*8+j ; B: n=lane&31, k=(lane>>5)*8+j
//   C/D: col=lane&31, row=(reg&3)+8*(reg>>2)+4*(lane>>5)
// permlane32_swap semantics (row1 of dst <-> row0 of src):
//   new_dst[l<32]=dst[l], new_dst[l>=32]=src[l-32];
//   new_src[l<32]=dst[l+32], new_src[l>=32]=src[l].
// pfv[ks] words = {s0[0], s1[0], s0[1], s1[1]} where s0=swap(a0,b0),
// s1=swap(a1,b1), a0=cvtpk(pe0,pe1) a1=cvtpk(pe2,pe3) b0=cvtpk(pe4,pe5)
// b1=cvtpk(pe6,pe7) -> both lane halves get their 8 consecutive kv values.
constexpr int NTt = Tn / 64;   // 32 kv tiles

struct PvOn  { static constexpr bool value = true;  };
struct PvOff { static constexpr bool value = false; };

__global__ __launch_bounds__(256) void attn_kernel(const bf16* __restrict__ Qh,
                                                   const bf16* __restrict__ Kh,
                                                   const bf16* __restrict__ VhT,
                                                   bf16* __restrict__ AO) {
  __shared__ bf16 Ks[2][64 * 64];   // [kv][d], chunk-swizzled, double-buffered
  __shared__ bf16 Vt[2][64 * 64];   // [d][kv], chunk-swizzled, double-buffered

  const int tid = threadIdx.x;
  const int w = tid >> 6, lane = tid & 63;
  const int l31 = lane & 31, hi = lane >> 5;
  const int id = blockIdx.x;
  const int bh = id & 31;           // low bits -> same-bh blocks share an XCD
  const int q0 = (id >> 5) * 128;
  const size_t hb = (size_t)bh * Tn * Dn;
  const size_t hbT = (size_t)bh * Dn * Tn;
  const int r8 = lane >> 3, c8 = lane & 7;
  const int soff = (c8 ^ r8) << 3;
  // fragment read addressing: row r, chunk c (8 bf16) lives at
  //   (r>>3)*512 + (r&7)*64 + ((c ^ (r&7))<<3)
  const int sw7 = l31 & 7;
  const int baseA = ((l31 >> 3) << 9) + (sw7 << 6);   // rows 0..31 (tile A)
  // tile B rows 32..63: +2048 elements

  // Q fragments (B-operand): lane owns q = q0 + w*32 + l31;
  // qf[ks] = Q[q][ks*16 + hi*8 .. +7]
  bf16x8 qf[4];
  {
    const bf16* qp = Qh + hb + (size_t)(q0 + w * 32 + l31) * Dn + hi * 8;
#pragma unroll
    for (int ks = 0; ks < 4; ks++) qf[ks] = *(const bf16x8*)(qp + ks * 16);
  }

  f32x16 o0 = {}, o1 = {};
  float l_run = 0.f;
  bf16x8 vf0[4], vf1[4];   // V^T frags of tile t (dtile 0/1), consumed iter t+1
  bf16x8 pfv[4];           // P frags of tile t, consumed iter t+1

  // prologue: stage tile 0 into buffer 0 (4 loads/wave)
  for (int i = 0; i < 2; i++) {
    int p = w * 2 + i;
    async_cp16(&Ks[0][p * 512], &Kh[hb + (size_t)(p * 8 + r8) * Dn + soff]);
    async_cp16(&Vt[0][p * 512], &VhT[hbT + (size_t)(p * 8 + r8) * Tn + soff]);
  }
  __syncthreads();

  auto body = [&](int kt, auto pvtag) {
    constexpr bool PV = decltype(pvtag)::value;
    const int cur = kt & 1;
    // prefetch next tile into the other buffer (readers passed last barrier)
    if (kt + 1 < NTt) {
      const int nxt = cur ^ 1;
      const int t1 = (kt + 1) * 64;
      for (int i = 0; i < 2; i++) {
        int p = w * 2 + i;
        async_cp16(&Ks[nxt][p * 512], &Kh[hb + (size_t)(t1 + p * 8 + r8) * Dn + soff]);
        async_cp16(&Vt[nxt][p * 512], &VhT[hbT + (size_t)(p * 8 + r8) * Tn + t1 + soff]);
      }
    }

    // S^T = K Q^T : sA = kv 0..31, sB = kv 32..63 (lane col = its q)
    f32x16 sA = {}, sB = {};
    const bf16* ksb = &Ks[cur][0];
    __builtin_amdgcn_s_setprio(1);
#pragma unroll
    for (int ks = 0; ks < 4; ks++) {
      const int off = (((ks * 2 + hi) ^ sw7) << 3);
      bf16x8 kfA = *(const bf16x8*)(ksb + baseA + off);
      bf16x8 kfB = *(const bf16x8*)(ksb + 2048 + baseA + off);
      sA = MFMA32(kfA, qf[ks], sA);
      sB = MFMA32(kfB, qf[ks], sB);
    }
    __builtin_amdgcn_s_setprio(0);

    // exp(t) interleaved with PV(t-1): independent streams keep VALU+MFMA fed
    float peA[16], peB[16];
    float r0 = 0.f, r1 = 0.f;
#pragma unroll
    for (int gq = 0; gq < 4; gq++) {
      float e0 = __builtin_amdgcn_exp2f(sA[gq * 4 + 0]);
      float e1 = __builtin_amdgcn_exp2f(sA[gq * 4 + 1]);
      float e2 = __builtin_amdgcn_exp2f(sA[gq * 4 + 2]);
      float e3 = __builtin_amdgcn_exp2f(sA[gq * 4 + 3]);
      peA[gq * 4 + 0] = e0; peA[gq * 4 + 1] = e1;
      peA[gq * 4 + 2] = e2; peA[gq * 4 + 3] = e3;
      r0 += e0 + e1; r1 += e2 + e3;
      if constexpr (PV) o0 = MFMA32(vf0[gq], pfv[gq], o0);
    }
#pragma unroll
    for (int gq = 0; gq < 4; gq++) {
      float e0 = __builtin_amdgcn_exp2f(sB[gq * 4 + 0]);
      float e1 = __builtin_amdgcn_exp2f(sB[gq * 4 + 1]);
      float e2 = __builtin_amdgcn_exp2f(sB[gq * 4 + 2]);
      float e3 = __builtin_amdgcn_exp2f(sB[gq * 4 + 3]);
      peB[gq * 4 + 0] = e0; peB[gq * 4 + 1] = e1;
      peB[gq * 4 + 2] = e2; peB[gq * 4 + 3] = e3;
      r0 += e0 + e1; r1 += e2 + e3;
      if constexpr (PV) o1 = MFMA32(vf1[gq], pfv[gq], o1);
    }
    l_run += r0 + r1;

    // pack P in-register: pfv[0..1] from tile A (kv 0..31), pfv[2..3] tile B
    {
      unsigned a0 = cvtpk(peA[0], peA[1]),  a1 = cvtpk(peA[2], peA[3]);
      unsigned b0 = cvtpk(peA[4], peA[5]),  b1 = cvtpk(peA[6], peA[7]);
      auto s0 = __builtin_amdgcn_permlane32_swap(a0, b0, false, false);
      auto s1 = __builtin_amdgcn_permlane32_swap(a1, b1, false, false);
      u32x4 w0 = {s0[0], s1[0], s0[1], s1[1]};
      pfv[0] = __builtin_bit_cast(bf16x8, w0);
      a0 = cvtpk(peA[8], peA[9]);   a1 = cvtpk(peA[10], peA[11]);
      b0 = cvtpk(peA[12], peA[13]); b1 = cvtpk(peA[14], peA[15]);
      s0 = __builtin_amdgcn_permlane32_swap(a0, b0, false, false);
      s1 = __builtin_amdgcn_permlane32_swap(a1, b1, false, false);
      u32x4 w1 = {s0[0], s1[0], s0[1], s1[1]};
      pfv[1] = __builtin_bit_cast(bf16x8, w1);
      a0 = cvtpk(peB[0], peB[1]);   a1 = cvtpk(peB[2], peB[3]);
      b0 = cvtpk(peB[4], peB[5]);   b1 = cvtpk(peB[6], peB[7]);
      s0 = __builtin_amdgcn_permlane32_swap(a0, b0, false, false);
      s1 = __builtin_amdgcn_permlane32_swap(a1, b1, false, false);
      u32x4 w2 = {s0[0], s1[0], s0[1], s1[1]};
      pfv[2] = __builtin_bit_cast(bf16x8, w2);
      a0 = cvtpk(peB[8], peB[9]);   a1 = cvtpk(peB[10], peB[11]);
      b0 = cvtpk(peB[12], peB[13]); b1 = cvtpk(peB[14], peB[15]);
      s0 = __builtin_amdgcn_permlane32_swap(a0, b0, false, false);
      s1 = __builtin_amdgcn_permlane32_swap(a1, b1, false, false);
      u32x4 w3 = {s0[0], s1[0], s0[1], s1[1]};
      pfv[3] = __builtin_bit_cast(bf16x8, w3);
    }

    // V^T frags for next iter's PV; latency hidden under barrier + next S
    {
      const bf16* vtb = &Vt[cur][0];
#pragma unroll
      for (int ks = 0; ks < 4; ks++) {
        const int off = (((ks * 2 + hi) ^ sw7) << 3);
        vf0[ks] = *(const bf16x8*)(vtb + baseA + off);
        vf1[ks] = *(const bf16x8*)(vtb + 2048 + baseA + off);
      }
    }

    __syncthreads();  // all waves done with cur buffers; drains prefetch vmcnt
  };

  body(0, PvOff{});
  for (int kt = 1; kt < NTt; kt++) body(kt, PvOn{});

  // epilogue PV for the last tile
  __builtin_amdgcn_s_setprio(1);
#pragma unroll
  for (int ks = 0; ks < 4; ks++) {
    o0 = MFMA32(vf0[ks], pfv[ks], o0);
    o1 = MFMA32(vf1[ks], pfv[ks], o1);
  }
  __builtin_amdgcn_s_setprio(0);

  // l: lane holds half the kv rows; partner (lane^32) holds the rest
  float l = l_run + __shfl_xor(l_run, 32);
  float inv = 1.0f / l;
  const int b = bh >> 4, h = bh & 15;
  const int q = q0 + w * 32 + l31;
  bf16* orow = AO + (size_t)(b * Tn + q) * Cn + h * Dn;
#pragma unroll
  for (int dt = 0; dt < 2; dt++) {
    const f32x16& oo = dt ? o1 : o0;
#pragma unroll
    for (int rq = 0; rq < 4; rq++) {
      bf16x4 ov = {(bf16)(oo[rq * 4 + 0] * inv), (bf16)(oo[rq * 4 + 1] * inv),
                   (bf16)(oo[rq * 4 + 2] * inv), (bf16)(oo[rq * 4 + 3] * inv)};
      *(bf16x4*)&orow[dt * 32 + rq * 8 + hi * 4] = ov;
    }
  }
}

extern "C" void kernel_launch(void* const* d_in, const int* in_sizes, int n_in,
                              void* d_out, int out_size, void* d_ws, size_t ws_size,
                              hipStream_t stream) {
  const float* query = (const float*)d_in[0];
  const float* key   = (const float*)d_in[1];
  const float* value = (const float*)d_in[2];
  const float* Wq = (const float*)d_in[3];
  const float* bq = (const float*)d_in[4];
  const float* Wk = (const float*)d_in[5];
  const float* bk = (const float*)d_in[6];
  const float* Wv = (const float*)d_in[7];
  const float* bv = (const float*)d_in[8];
  const float* Wo = (const float*)d_in[9];
  const float* bo = (const float*)d_in[10];

  bf16* p = (bf16*)d_ws;
  bf16* WqT = p; p += WSZ;
  bf16* WkT = p; p += WSZ;
  bf16* WvT = p; p += WSZ;
  bf16* WoT = p; p += WSZ;
  bf16* Xbf = p; p += 3 * XSZ;   // bf16 activations; reused as AO after QKV GEMM
  bf16* Qh = p; p += XSZ;
  bf16* Kh = p; p += XSZ;
  bf16* VhT = p; p += XSZ;
  bf16* AO = Xbf;

  TransArgs ta;
  ta.W[0] = Wq; ta.W[1] = Wk; ta.W[2] = Wv; ta.W[3] = Wo;
  ta.Wt[0] = WqT; ta.Wt[1] = WkT; ta.Wt[2] = WvT; ta.Wt[3] = WoT;
  transpose_convert<<<dim3(32, 32, 4), dim3(32, 8), 0, stream>>>(ta);

  ConvArgs ca;
  ca.src[0] = query; ca.src[1] = key; ca.src[2] = value;
  convert_bf16<<<dim3(XSZ / 2048, 3), 256, 0, stream>>>(ca, Xbf);

  GemmArgs ga;
  ga.A[0] = Xbf; ga.A[1] = Xbf + XSZ; ga.A[2] = Xbf + 2 * XSZ;
  ga.Bt[0] = WqT;  ga.Bt[1] = WkT; ga.Bt[2] = WvT;
  ga.bias[0] = bq; ga.bias[1] = bk; ga.bias[2] = bv;
  ga.out[0] = Qh;  ga.out[1] = Kh;  ga.out[2] = VhT;
  ga.scale[0] = 0.125f * LOG2E; ga.scale[1] = 1.0f; ga.scale[2] = 1.0f;
  ga.layout[0] = 1; ga.layout[1] = 1; ga.layout[2] = 2;
  gemm_kernel<128><<<dim3(Cn / 128, Mn / 128, 3), 256, 0, stream>>>(ga, Cn);

  attn_kernel<<<dim3(512), 256, 0, stream>>>(Qh, Kh, VhT, AO);

  GemmArgs gb;
  gb.A[0] = AO; gb.Bt[0] = WoT; gb.bias[0] = bo; gb.out[0] = d_out; gb.scale[0] = 1.0f;
  gb.layout[0] = 0;
  gb.A[1] = gb.A[2] = nullptr; gb.Bt[1] = gb.Bt[2] = nullptr;
  gb.bias[1] = gb.bias[2] = nullptr; gb.out[1] = gb.out[2] = nullptr;
  gb.scale[1] = gb.scale[2] = 1.0f; gb.layout[1] = gb.layout[2] = 0;
  gemm_kernel<64><<<dim3(Cn / 128, Mn / 64, 1), 256, 0, stream>>>(gb, Cn);
}